// Round 5
// baseline (338.381 us; speedup 1.0000x reference)
//
#include <hip/hip_runtime.h>

#define B_ 4
#define C_ 256
#define N_ 4096
#define INTER_ 32

typedef __attribute__((ext_vector_type(8))) short short8;
typedef __attribute__((ext_vector_type(4))) float f32x4;
typedef __attribute__((ext_vector_type(16))) float f32x16;
typedef __attribute__((ext_vector_type(4))) unsigned int u32x4;

#define VROW 80                    // padded LDS row stride (bytes), 16B-aligned
#define VTILE (256 * VROW)         // 20480 B
#define KTILE (32 * VROW)          // 2560 B
#define KOFF  (4 * VTILE)          // 81920
#define MLOFF (KOFF + 4 * KTILE)   // 92160
#define LDSSZ (MLOFF + 1024)

static __device__ __forceinline__ unsigned short f2bf(float f) {
    unsigned int u = __builtin_bit_cast(unsigned int, f);
    u += 0x7fff + ((u >> 16) & 1);   // round-to-nearest-even
    return (unsigned short)(u >> 16);
}

static __device__ __forceinline__ unsigned int cvtpk(float lo, float hi) {
    unsigned int r;
    asm("v_cvt_pk_bf16_f32 %0, %1, %2" : "=v"(r) : "v"(lo), "v"(hi));
    return r;
}

static __device__ __forceinline__ void pl32swap(unsigned int& a, unsigned int& b) {
    asm("v_permlane32_swap_b32 %0, %1" : "+v"(a), "+v"(b));
}

// ---------------- W prep: concat + bf16 convert ----------------
__global__ __launch_bounds__(256) void prep_kernel(
    const float* __restrict__ Wq, const float* __restrict__ Wk,
    const float* __restrict__ Wv, unsigned short* __restrict__ wb)
{
    int i = blockIdx.x * 256 + threadIdx.x;      // 0 .. 320*256-1
    int row = i >> 8, col = i & 255;
    float v;
    if (row < 32)      v = Wq[row * 256 + col];
    else if (row < 64) v = Wk[(row - 32) * 256 + col];
    else               v = Wv[(row - 64) * 256 + col];
    wb[i] = f2bf(v);
}

// ---------------- QKV projection as MFMA GEMM ----------------
// q,k: [b][n][32] bf16 (q pre-scaled). v: j-BLOCKED layout vblk[b][n/32][c][32]
// so a 32-key V tile is one contiguous 16KB chunk (coalesced attn staging).
__global__ __launch_bounds__(256) void qkv_kernel(
    const float* __restrict__ x, const unsigned short* __restrict__ wb,
    const float* __restrict__ bq, const float* __restrict__ bk,
    const float* __restrict__ bv,
    unsigned short* __restrict__ qb, unsigned short* __restrict__ kb,
    unsigned short* __restrict__ vblk)
{
    const int tid  = threadIdx.x;
    const int wave = tid >> 6;
    const int lane = tid & 63;
    const int l31  = lane & 31;
    const int h2   = lane >> 5;
    const int b    = blockIdx.x >> 6;
    const int n0   = (blockIdx.x & 63) * 64;

    __shared__ unsigned int xsh[64 * 129];   // [n][c/2] u32, row stride 129 dwords

    {
        const float* xb = x + ((size_t)b * C_ + 64 * wave) * N_ + n0 + lane;
        unsigned int* dst = xsh + (size_t)lane * 129 + 32 * wave;
        #pragma unroll 8
        for (int s = 0; s < 32; ++s) {
            float v0 = xb[(size_t)(2 * s) * N_];
            float v1 = xb[(size_t)(2 * s + 1) * N_];
            dst[s] = (unsigned int)f2bf(v0) | ((unsigned int)f2bf(v1) << 16);
        }
    }
    __syncthreads();

    const float rs = 0.17677669529663687f;   // 1/sqrt(32) folded into q

    #pragma unroll
    for (int u = 0; u < 5; ++u) {
        const int unit = wave + 4 * u;       // 0..19
        const int ch = unit >> 1;            // 0..9
        const int ns = unit & 1;
        const int ncol = n0 + 32 * ns + l31;

        const float* bias = (ch == 0) ? bq : (ch == 1) ? bk : (bv + (ch - 2) * 32);
        f32x16 acc;
        #pragma unroll
        for (int r = 0; r < 16; ++r)
            acc[r] = bias[(r & 3) + 8 * (r >> 2) + 4 * h2];

        const unsigned short* wrow = wb + ((size_t)(ch * 32 + l31)) * 256 + 8 * h2;
        const unsigned int*   xrow = xsh + (size_t)(32 * ns + l31) * 129 + 4 * h2;

        #pragma unroll
        for (int kk = 0; kk < 16; ++kk) {
            short8 wa = *reinterpret_cast<const short8*>(wrow + 16 * kk);
            short8 xf = *reinterpret_cast<const short8*>(xrow + 8 * kk);
            acc = __builtin_amdgcn_mfma_f32_32x32x16_bf16(wa, xf, acc, 0, 0, 0);
        }

        if (ch < 2) {
            unsigned short* dst = (ch ? kb : qb) + ((size_t)b * N_ + ncol) * 32;
            const float sc = ch ? 1.0f : rs;
            #pragma unroll
            for (int q = 0; q < 4; ++q) {
                unsigned int w0 = (unsigned int)f2bf(acc[4 * q] * sc)
                                | ((unsigned int)f2bf(acc[4 * q + 1] * sc) << 16);
                unsigned int w1 = (unsigned int)f2bf(acc[4 * q + 2] * sc)
                                | ((unsigned int)f2bf(acc[4 * q + 3] * sc) << 16);
                unsigned int* p = reinterpret_cast<unsigned int*>(dst + 4 * h2 + 8 * q);
                p[0] = w0; p[1] = w1;
            }
        } else {
            const int jt = (n0 >> 5) + ns;
            unsigned short* vdst = vblk + (((size_t)b * (N_ / 32) + jt) * C_) * 32;
            #pragma unroll
            for (int r = 0; r < 16; ++r) {
                const int c = (ch - 2) * 32 + (r & 3) + 8 * (r >> 2) + 4 * h2;
                vdst[(size_t)c * 32 + l31] = f2bf(acc[r]);   // coalesced over l31
            }
        }
    }
}

// ---------------- Flash attention: LDS-staged tiles, swapped-operand MFMA ----
// grid (N/64, B), block 256 = 4 waves = 2 i-waves x 2 j-halves.
// Per step (32 keys): each j-half stages V(16KB)+K(2KB) coalesced from global
// into pad-80 LDS rows (reg-staged, double-buffered, loads for t+1 issued
// before compute of t, ONE barrier/step). Waves read A-frags from LDS
// (scatter is free there), run lane-local online softmax (i = lane&31),
// in-register P via cvt_pk+permlane32_swap, 16 PV MFMAs. 2-way j-combine.
__global__ __launch_bounds__(256, 1) void attn_kernel(
    const unsigned short* __restrict__ qb, const unsigned short* __restrict__ kb,
    const unsigned short* __restrict__ vblk,
    const float* __restrict__ x, const float* __restrict__ gamma,
    float* __restrict__ out)
{
    const int tid  = threadIdx.x;
    const int wave = tid >> 6;
    const int lane = tid & 63;
    const int l31  = lane & 31;
    const int h2   = lane >> 5;
    const int iw   = wave & 1;     // i-wave
    const int jh   = wave >> 1;    // j-half
    const int b  = blockIdx.y;
    const int i0 = blockIdx.x * 64;
    const int iq = i0 + 32 * iw;   // this wave's 32 query rows start

    __shared__ char lds[LDSSZ];
    char* vt0 = lds + (2 * jh) * VTILE;          // double buffer pair for this jh
    char* vt1 = lds + (2 * jh + 1) * VTILE;
    char* kt0 = lds + KOFF + (2 * jh) * KTILE;
    char* kt1 = lds + KOFF + (2 * jh + 1) * KTILE;
    float* msh = (float*)(lds + MLOFF);          // [iw*2+jh][32]
    float* lsh = msh + 128;

    const unsigned short* vsrc_base = vblk + ((size_t)b * (N_ / 32)) * C_ * 32;
    const unsigned short* ksrc_base = kb + (size_t)b * N_ * INTER_;

    // Q B-fragments for rows iq..iq+31 (one-time scattered load, fine)
    short8 qf0 = *reinterpret_cast<const short8*>(
        qb + ((size_t)b * N_ + iq + l31) * INTER_ + 8 * h2);
    short8 qf1 = *reinterpret_cast<const short8*>(
        qb + ((size_t)b * N_ + iq + l31) * INTER_ + 8 * h2 + 16);

    f32x16 acc[8];
    #pragma unroll
    for (int g = 0; g < 8; ++g)
        #pragma unroll
        for (int r = 0; r < 16; ++r) acc[g][r] = 0.f;

    float m_run = 0.f;   // defer-max init
    float l_run = 0.f;
    const f32x16 z16 = {};

    u32x4 vreg[8]; u32x4 kreg;

    // ---- prologue: stage tile 0 of this j-half ----
    {
        const int jtg = jh * 64;
        const u32x4* vs = reinterpret_cast<const u32x4*>(vsrc_base + (size_t)jtg * 8192);
        #pragma unroll
        for (int t = 0; t < 8; ++t) vreg[t] = vs[iw * 512 + t * 64 + lane];
        const u32x4* ks = reinterpret_cast<const u32x4*>(ksrc_base + (size_t)jtg * 1024);
        kreg = ks[iw * 64 + lane];
        #pragma unroll
        for (int t = 0; t < 8; ++t) {
            int n = iw * 512 + t * 64 + lane;
            *reinterpret_cast<u32x4*>(vt0 + (n >> 2) * VROW + (n & 3) * 16) = vreg[t];
        }
        int n = iw * 64 + lane;
        *reinterpret_cast<u32x4*>(kt0 + (n >> 2) * VROW + (n & 3) * 16) = kreg;
    }
    __syncthreads();

    #pragma unroll 1
    for (int jt = 0; jt < 64; ++jt) {
        const char* vt_ = (jt & 1) ? vt1 : vt0;
        const char* kt_ = (jt & 1) ? kt1 : kt0;
        char* vtn = (jt & 1) ? vt0 : vt1;
        char* ktn = (jt & 1) ? kt0 : kt1;

        // issue next tile's global loads early (latency hides under compute)
        if (jt < 63) {
            const int jtg = jh * 64 + jt + 1;
            const u32x4* vs = reinterpret_cast<const u32x4*>(vsrc_base + (size_t)jtg * 8192);
            #pragma unroll
            for (int t = 0; t < 8; ++t) vreg[t] = vs[iw * 512 + t * 64 + lane];
            const u32x4* ks = reinterpret_cast<const u32x4*>(ksrc_base + (size_t)jtg * 1024);
            kreg = ks[iw * 64 + lane];
        }

        // ---- QK^T (swapped): S^T[j][i] ----
        short8 ka0 = *reinterpret_cast<const short8*>(kt_ + l31 * VROW + h2 * 16);
        short8 ka1 = *reinterpret_cast<const short8*>(kt_ + l31 * VROW + (h2 + 2) * 16);
        f32x16 s = __builtin_amdgcn_mfma_f32_32x32x16_bf16(ka0, qf0, z16, 0, 0, 0);
        s = __builtin_amdgcn_mfma_f32_32x32x16_bf16(ka1, qf1, s, 0, 0, 0);

        // ---- online softmax, lane-local (i = l31) ----
        float a0 = fmaxf(s[0], s[8]),  a1 = fmaxf(s[1], s[9]);
        float a2 = fmaxf(s[2], s[10]), a3 = fmaxf(s[3], s[11]);
        float a4 = fmaxf(s[4], s[12]), a5 = fmaxf(s[5], s[13]);
        float a6 = fmaxf(s[6], s[14]), a7 = fmaxf(s[7], s[15]);
        a0 = fmaxf(a0, a4); a1 = fmaxf(a1, a5); a2 = fmaxf(a2, a6); a3 = fmaxf(a3, a7);
        float smax = fmaxf(fmaxf(a0, a1), fmaxf(a2, a3));

        if (__any(smax > m_run + 5.5f)) {
            float sm2 = fmaxf(smax, __shfl_xor(smax, 32));
            float mnew = fmaxf(m_run, sm2);
            float corr = __expf(m_run - mnew);
            m_run = mnew;
            l_run *= corr;
            #pragma unroll
            for (int g = 0; g < 8; ++g)
                #pragma unroll
                for (int r = 0; r < 16; ++r) acc[g][r] *= corr;
        }

        float p[16];
        float lsum = 0.f;
        #pragma unroll
        for (int r = 0; r < 16; ++r) { p[r] = __expf(s[r] - m_run); lsum += p[r]; }
        l_run += lsum;

        unsigned int X0 = cvtpk(p[0],  p[1]),  X1 = cvtpk(p[2],  p[3]);
        unsigned int Y0 = cvtpk(p[4],  p[5]),  Y1 = cvtpk(p[6],  p[7]);
        unsigned int W0 = cvtpk(p[8],  p[9]),  W1 = cvtpk(p[10], p[11]);
        unsigned int V0 = cvtpk(p[12], p[13]), V1 = cvtpk(p[14], p[15]);
        pl32swap(X0, Y0); pl32swap(X1, Y1);
        pl32swap(W0, V0); pl32swap(W1, V1);
        short8 pb0 = __builtin_bit_cast(short8, u32x4{X0, X1, Y0, Y1});
        short8 pb1 = __builtin_bit_cast(short8, u32x4{W0, W1, V0, V1});

        // ---- PV: A-frags from LDS (scatter-free) ----
        __builtin_amdgcn_s_setprio(1);
        #pragma unroll
        for (int g = 0; g < 8; ++g) {
            const char* vrow = vt_ + (32 * g + l31) * VROW;
            short8 va0 = *reinterpret_cast<const short8*>(vrow + h2 * 16);
            short8 va1 = *reinterpret_cast<const short8*>(vrow + (h2 + 2) * 16);
            acc[g] = __builtin_amdgcn_mfma_f32_32x32x16_bf16(va0, pb0, acc[g], 0, 0, 0);
            acc[g] = __builtin_amdgcn_mfma_f32_32x32x16_bf16(va1, pb1, acc[g], 0, 0, 0);
        }
        __builtin_amdgcn_s_setprio(0);

        // ---- write next tile to the alternate buffer, then barrier ----
        if (jt < 63) {
            #pragma unroll
            for (int t = 0; t < 8; ++t) {
                int n = iw * 512 + t * 64 + lane;
                *reinterpret_cast<u32x4*>(vtn + (n >> 2) * VROW + (n & 3) * 16) = vreg[t];
            }
            int n = iw * 64 + lane;
            *reinterpret_cast<u32x4*>(ktn + (n >> 2) * VROW + (n & 3) * 16) = kreg;
        }
        __syncthreads();
    }

    // ---- 2-way j-combine (per i-wave) ----
    float l_tot = l_run + __shfl_xor(l_run, 32);
    if (lane < 32) {
        msh[(iw * 2 + jh) * 32 + lane] = m_run;
        lsh[(iw * 2 + jh) * 32 + lane] = l_tot;
    }
    __syncthreads();

    const float m0 = msh[(iw * 2 + 0) * 32 + l31];
    const float m1 = msh[(iw * 2 + 1) * 32 + l31];
    const float M  = fmaxf(m0, m1);
    const float L  = __expf(m0 - M) * lsh[(iw * 2 + 0) * 32 + l31]
                   + __expf(m1 - M) * lsh[(iw * 2 + 1) * 32 + l31];
    const float wgt = __expf(m_run - M);

    #pragma unroll
    for (int g = 0; g < 8; ++g)
        #pragma unroll
        for (int r = 0; r < 16; ++r) acc[g][r] *= wgt;

    // exchange complement g-slices through LDS (reuses V-tile area)
    f32x4* cbuf = reinterpret_cast<f32x4*>(lds);
    const int wr_region = iw * 2 + (1 - jh);     // partner reads this
    #pragma unroll
    for (int gl = 0; gl < 4; ++gl) {
        const int g = (1 - jh) * 4 + gl;
        #pragma unroll
        for (int r4 = 0; r4 < 4; ++r4) {
            f32x4 t;
            #pragma unroll
            for (int e = 0; e < 4; ++e) t[e] = acc[g][4 * r4 + e];
            cbuf[((wr_region * 4 + gl) * 4 + r4) * 64 + lane] = t;
        }
    }
    __syncthreads();

    // merge own g-slice + partner's contribution; store with residual
    const float gma  = gamma[0];
    const float invL = 1.f / L;
    const int rd_region = iw * 2 + jh;
    #pragma unroll
    for (int gl = 0; gl < 4; ++gl) {
        const int g = jh * 4 + gl;
        #pragma unroll
        for (int r4 = 0; r4 < 4; ++r4) {
            f32x4 t = cbuf[((rd_region * 4 + gl) * 4 + r4) * 64 + lane];
            #pragma unroll
            for (int e = 0; e < 4; ++e) {
                const float v = acc[g][4 * r4 + e] + t[e];
                const int c = 32 * g + e + 8 * r4 + 4 * h2;
                const size_t off = ((size_t)b * C_ + c) * N_ + iq + l31;
                out[off] = gma * v * invL + x[off];
            }
        }
    }
}

extern "C" void kernel_launch(void* const* d_in, const int* in_sizes, int n_in,
                              void* d_out, int out_size, void* d_ws, size_t ws_size,
                              hipStream_t stream) {
    const float* x     = (const float*)d_in[0];
    const float* Wq    = (const float*)d_in[1];
    const float* bq    = (const float*)d_in[2];
    const float* Wk    = (const float*)d_in[3];
    const float* bk    = (const float*)d_in[4];
    const float* Wv    = (const float*)d_in[5];
    const float* bv    = (const float*)d_in[6];
    const float* gamma = (const float*)d_in[7];
    float* out = (float*)d_out;

    unsigned short* ws = (unsigned short*)d_ws;
    unsigned short* qb   = ws;                                  // B*N*32 bf16
    unsigned short* kb   = qb + (size_t)B_ * N_ * INTER_;       // B*N*32 bf16
    unsigned short* vblk = kb + (size_t)B_ * N_ * INTER_;       // B*(N/32)*C*32 bf16
    unsigned short* wb   = vblk + (size_t)B_ * C_ * N_;         // 320*256 bf16

    prep_kernel<<<dim3(320), 256, 0, stream>>>(Wq, Wk, Wv, wb);
    qkv_kernel<<<dim3(B_ * (N_ / 64)), 256, 0, stream>>>(
        x, wb, bq, bk, bv, qb, kb, vblk);
    attn_kernel<<<dim3(N_ / 64, B_), 256, 0, stream>>>(
        qb, kb, vblk, x, gamma, out);
}

// Round 6
// 84.602 us; speedup vs baseline: 3.9997x; 3.9997x over previous
//
#include <hip/hip_runtime.h>

#define B_ 4
#define C_ 256
#define N_ 4096
#define INTER_ 32

typedef __attribute__((ext_vector_type(8))) short short8;
typedef __attribute__((ext_vector_type(4))) float f32x4;
typedef __attribute__((ext_vector_type(16))) float f32x16;
typedef __attribute__((ext_vector_type(4))) unsigned int u32x4;

#define TILEB 18432              // staged bytes per j-tile: V 16KB + K 2KB
#define NSTG  (8 * TILEB)        // 4 jq * 2 buf = 147456 B

static __device__ __forceinline__ unsigned short f2bf(float f) {
    unsigned int u = __builtin_bit_cast(unsigned int, f);
    u += 0x7fff + ((u >> 16) & 1);   // round-to-nearest-even
    return (unsigned short)(u >> 16);
}

static __device__ __forceinline__ unsigned int cvtpk(float lo, float hi) {
    unsigned int r;
    asm("v_cvt_pk_bf16_f32 %0, %1, %2" : "=v"(r) : "v"(lo), "v"(hi));
    return r;
}

static __device__ __forceinline__ void pl32swap(unsigned int& a, unsigned int& b) {
    asm("v_permlane32_swap_b32 %0, %1" : "+v"(a), "+v"(b));
}

static __device__ __forceinline__ void gload16(const void* g, void* l) {
    __builtin_amdgcn_global_load_lds(
        (const __attribute__((address_space(1))) void*)g,
        (__attribute__((address_space(3))) void*)l, 16, 0, 0);
}

// ---------------- W prep: concat + bf16 convert ----------------
__global__ __launch_bounds__(256) void prep_kernel(
    const float* __restrict__ Wq, const float* __restrict__ Wk,
    const float* __restrict__ Wv, unsigned short* __restrict__ wb)
{
    int i = blockIdx.x * 256 + threadIdx.x;      // 0 .. 320*256-1
    int row = i >> 8, col = i & 255;
    float v;
    if (row < 32)      v = Wq[row * 256 + col];
    else if (row < 64) v = Wk[(row - 32) * 256 + col];
    else               v = Wv[(row - 64) * 256 + col];
    wb[i] = f2bf(v);
}

// ---------------- QKV projection as MFMA GEMM ----------------
// q: [b][n][32] bf16 (pre-scaled by 1/sqrt(32)).
// K/V are emitted in MFMA-FRAGMENT-LINEAR tiles so the attn kernel can stage
// them with global_load_lds (linear dest) and read with lane-linear
// ds_read_b128 (conflict-free):
//   kfrag[b][jt] = 1024 el: el = chunk*512 + lane*8 + t,
//     holds K[j = jt*32 + (lane&31)][kdim = chunk*16 + 8*(lane>>5) + t]
//   vfrag[b][jt][g] = 1024 el: el = chunk*512 + lane*8 + t,
//     holds V[c = 32g + (lane&31)][j = jt*32 + chunk*16 + 8*(lane>>5) + t]
__global__ __launch_bounds__(256) void qkv_kernel(
    const float* __restrict__ x, const unsigned short* __restrict__ wb,
    const float* __restrict__ bq, const float* __restrict__ bk,
    const float* __restrict__ bv,
    unsigned short* __restrict__ qb, unsigned short* __restrict__ kfrag,
    unsigned short* __restrict__ vfrag)
{
    const int tid  = threadIdx.x;
    const int wave = tid >> 6;
    const int lane = tid & 63;
    const int l31  = lane & 31;
    const int h2   = lane >> 5;
    const int b    = blockIdx.x >> 6;
    const int n0   = (blockIdx.x & 63) * 64;

    __shared__ unsigned int xsh[64 * 129];   // [n][c/2] u32, row stride 129 dwords

    {
        const float* xb = x + ((size_t)b * C_ + 64 * wave) * N_ + n0 + lane;
        unsigned int* dst = xsh + (size_t)lane * 129 + 32 * wave;
        #pragma unroll 8
        for (int s = 0; s < 32; ++s) {
            float v0 = xb[(size_t)(2 * s) * N_];
            float v1 = xb[(size_t)(2 * s + 1) * N_];
            dst[s] = (unsigned int)f2bf(v0) | ((unsigned int)f2bf(v1) << 16);
        }
    }
    __syncthreads();

    const float rs = 0.17677669529663687f;   // 1/sqrt(32) folded into q

    #pragma unroll
    for (int u = 0; u < 5; ++u) {
        const int unit = wave + 4 * u;       // 0..19
        const int ch = unit >> 1;            // 0..9
        const int ns = unit & 1;
        const int ncol = n0 + 32 * ns + l31;
        const int jt = (n0 >> 5) + ns;

        const float* bias = (ch == 0) ? bq : (ch == 1) ? bk : (bv + (ch - 2) * 32);
        f32x16 acc;
        #pragma unroll
        for (int r = 0; r < 16; ++r)
            acc[r] = bias[(r & 3) + 8 * (r >> 2) + 4 * h2];

        const unsigned short* wrow = wb + ((size_t)(ch * 32 + l31)) * 256 + 8 * h2;
        const unsigned int*   xrow = xsh + (size_t)(32 * ns + l31) * 129 + 4 * h2;

        #pragma unroll
        for (int kk = 0; kk < 16; ++kk) {
            short8 wa = *reinterpret_cast<const short8*>(wrow + 16 * kk);
            short8 xf = *reinterpret_cast<const short8*>(xrow + 8 * kk);
            acc = __builtin_amdgcn_mfma_f32_32x32x16_bf16(wa, xf, acc, 0, 0, 0);
        }

        if (ch == 0) {
            unsigned short* dst = qb + ((size_t)b * N_ + ncol) * 32;
            #pragma unroll
            for (int q = 0; q < 4; ++q) {
                unsigned int w0 = (unsigned int)f2bf(acc[4 * q] * rs)
                                | ((unsigned int)f2bf(acc[4 * q + 1] * rs) << 16);
                unsigned int w1 = (unsigned int)f2bf(acc[4 * q + 2] * rs)
                                | ((unsigned int)f2bf(acc[4 * q + 3] * rs) << 16);
                unsigned int* p = reinterpret_cast<unsigned int*>(dst + 4 * h2 + 8 * q);
                p[0] = w0; p[1] = w1;
            }
        } else if (ch == 1) {
            // K fragment tile: acc[r] = K[kdim=co][j_local=l31]
            unsigned short* kt = kfrag + ((size_t)b * 128 + jt) * 1024;
            #pragma unroll
            for (int r = 0; r < 16; ++r) {
                const int co = (r & 3) + 8 * (r >> 2) + 4 * h2;
                const int addr = ((co >> 4) << 9) + ((l31 + 32 * ((co >> 3) & 1)) << 3)
                               + (co & 7);
                kt[addr] = f2bf(acc[r]);
            }
        } else {
            // V fragment tile: acc[r] = V[c=32g+co][j_local=l31]
            const int g = ch - 2;
            unsigned short* vt_ = vfrag + (((size_t)b * 128 + jt) * 8 + g) * 1024;
            #pragma unroll
            for (int r = 0; r < 16; ++r) {
                const int co = (r & 3) + 8 * (r >> 2) + 4 * h2;
                const int addr = ((l31 >> 4) << 9) + ((co + 32 * ((l31 >> 3) & 1)) << 3)
                               + (l31 & 7);
                vt_[addr] = f2bf(acc[r]);
            }
        }
    }
}

// ---------------- Flash attention: gload_lds-staged fragment tiles ----------
// grid (N/64, B), block 512 = 8 waves = 4 j-quarters x 2 q-subwaves.
// Per 32-key step: each jq-pair stages its 18KB tile via 18 global_load_lds
// (9 per wave, zero VGPR, coalesced, linear LDS). All frag reads are
// lane-linear ds_read_b128 (conflict-free). Swapped-operand MFMA flash loop
// (i = lane&31 lane-local softmax), 4-way phased j-combine reusing the LDS.
__global__ __launch_bounds__(512) void attn_kernel(
    const unsigned short* __restrict__ qb, const unsigned short* __restrict__ kfrag,
    const unsigned short* __restrict__ vfrag,
    const float* __restrict__ x, const float* __restrict__ gamma,
    float* __restrict__ out)
{
    const int tid  = threadIdx.x;
    const int wave = tid >> 6;
    const int lane = tid & 63;
    const int l31  = lane & 31;
    const int h2   = lane >> 5;
    const int jq   = wave >> 1;
    const int qs   = wave & 1;
    const int b    = blockIdx.y;
    const int iq   = blockIdx.x * 64 + 32 * qs;

    __shared__ char lds[NSTG];
    __shared__ float m_sh[8][32];
    __shared__ float l_sh[8][32];

    const unsigned short* vtb = vfrag + (size_t)b * 128 * 8192;
    const unsigned short* ktb = kfrag + (size_t)b * 128 * 1024;

    char* reg0 = lds + (jq * 2) * TILEB;
    char* reg1 = reg0 + TILEB;

    // Q B-fragments (one-time scattered load)
    short8 qf0 = *reinterpret_cast<const short8*>(
        qb + ((size_t)b * N_ + iq + l31) * 32 + 8 * h2);
    short8 qf1 = *reinterpret_cast<const short8*>(
        qb + ((size_t)b * N_ + iq + l31) * 32 + 8 * h2 + 16);

    f32x16 acc[8];
    #pragma unroll
    for (int g = 0; g < 8; ++g)
        #pragma unroll
        for (int r = 0; r < 16; ++r) acc[g][r] = 0.f;

    float m_run = 0.f;   // defer-max init
    float l_run = 0.f;
    const f32x16 z16 = {};

    // ---- prologue: stage tile 0 ----
    {
        const char* vs = (const char*)(vtb + (size_t)(jq * 32) * 8192);
        const char* ks = (const char*)(ktb + (size_t)(jq * 32) * 1024);
        #pragma unroll
        for (int s2 = 0; s2 < 9; ++s2) {
            const int off = qs * 9216 + s2 * 1024;
            const char* g = (off < 16384) ? (vs + off) : (ks + (off - 16384));
            gload16(g + lane * 16, reg0 + off);
        }
    }
    __syncthreads();

    #pragma unroll 1
    for (int t = 0; t < 32; ++t) {
        char* cur = (t & 1) ? reg1 : reg0;
        char* nxt = (t & 1) ? reg0 : reg1;

        // stage next tile (T3 2-phase: issue before compute)
        if (t < 31) {
            const int jtg = jq * 32 + t + 1;
            const char* vs = (const char*)(vtb + (size_t)jtg * 8192);
            const char* ks = (const char*)(ktb + (size_t)jtg * 1024);
            #pragma unroll
            for (int s2 = 0; s2 < 9; ++s2) {
                const int off = qs * 9216 + s2 * 1024;
                const char* g = (off < 16384) ? (vs + off) : (ks + (off - 16384));
                gload16(g + lane * 16, nxt + off);
            }
        }

        // ---- QK^T (swapped): S^T[j][i] ----
        const char* kt_ = cur + 16384;
        short8 ka0 = *reinterpret_cast<const short8*>(kt_ + lane * 16);
        short8 ka1 = *reinterpret_cast<const short8*>(kt_ + 1024 + lane * 16);
        f32x16 s = __builtin_amdgcn_mfma_f32_32x32x16_bf16(ka0, qf0, z16, 0, 0, 0);
        s = __builtin_amdgcn_mfma_f32_32x32x16_bf16(ka1, qf1, s, 0, 0, 0);

        // ---- online softmax, lane-local (i = l31) ----
        float a0 = fmaxf(s[0], s[8]),  a1 = fmaxf(s[1], s[9]);
        float a2 = fmaxf(s[2], s[10]), a3 = fmaxf(s[3], s[11]);
        float a4 = fmaxf(s[4], s[12]), a5 = fmaxf(s[5], s[13]);
        float a6 = fmaxf(s[6], s[14]), a7 = fmaxf(s[7], s[15]);
        a0 = fmaxf(a0, a4); a1 = fmaxf(a1, a5); a2 = fmaxf(a2, a6); a3 = fmaxf(a3, a7);
        float smax = fmaxf(fmaxf(a0, a1), fmaxf(a2, a3));

        if (__any(smax > m_run + 5.5f)) {
            float sm2 = fmaxf(smax, __shfl_xor(smax, 32));
            float mnew = fmaxf(m_run, sm2);
            float corr = __expf(m_run - mnew);
            m_run = mnew;
            l_run *= corr;
            #pragma unroll
            for (int g = 0; g < 8; ++g)
                #pragma unroll
                for (int r = 0; r < 16; ++r) acc[g][r] *= corr;
        }

        float p[16];
        float lsum = 0.f;
        #pragma unroll
        for (int r = 0; r < 16; ++r) { p[r] = __expf(s[r] - m_run); lsum += p[r]; }
        l_run += lsum;

        unsigned int X0 = cvtpk(p[0],  p[1]),  X1 = cvtpk(p[2],  p[3]);
        unsigned int Y0 = cvtpk(p[4],  p[5]),  Y1 = cvtpk(p[6],  p[7]);
        unsigned int W0 = cvtpk(p[8],  p[9]),  W1 = cvtpk(p[10], p[11]);
        unsigned int V0 = cvtpk(p[12], p[13]), V1 = cvtpk(p[14], p[15]);
        pl32swap(X0, Y0); pl32swap(X1, Y1);
        pl32swap(W0, V0); pl32swap(W1, V1);
        short8 pb0 = __builtin_bit_cast(short8, u32x4{X0, X1, Y0, Y1});
        short8 pb1 = __builtin_bit_cast(short8, u32x4{W0, W1, V0, V1});

        // ---- PV: lane-linear V fragment reads from LDS ----
        __builtin_amdgcn_s_setprio(1);
        #pragma unroll
        for (int g = 0; g < 8; ++g) {
            short8 va0 = *reinterpret_cast<const short8*>(cur + g * 2048 + lane * 16);
            short8 va1 = *reinterpret_cast<const short8*>(cur + g * 2048 + 1024 + lane * 16);
            acc[g] = __builtin_amdgcn_mfma_f32_32x32x16_bf16(va0, pb0, acc[g], 0, 0, 0);
            acc[g] = __builtin_amdgcn_mfma_f32_32x32x16_bf16(va1, pb1, acc[g], 0, 0, 0);
        }
        __builtin_amdgcn_s_setprio(0);

        __syncthreads();   // drains vmcnt (next tile landed) + guards buffers
    }

    // ---- 4-way j-combine ----
    float l_tot = l_run + __shfl_xor(l_run, 32);
    if (lane < 32) { m_sh[wave][lane] = m_run; l_sh[wave][lane] = l_tot; }
    __syncthreads();

    float M = -1e30f, L = 0.f;
    #pragma unroll
    for (int w2 = 0; w2 < 4; ++w2) M = fmaxf(M, m_sh[w2 * 2 + qs][l31]);
    #pragma unroll
    for (int w2 = 0; w2 < 4; ++w2)
        L += __expf(m_sh[w2 * 2 + qs][l31] - M) * l_sh[w2 * 2 + qs][l31];
    const float wgt = __expf(m_run - M);
    #pragma unroll
    for (int g = 0; g < 8; ++g)
        #pragma unroll
        for (int r = 0; r < 16; ++r) acc[g][r] *= wgt;

    // phase A: jq2,jq3 dump -> D[(jq-2)*2+qs]; jq0,jq1 add
    if (jq >= 2) {
        f32x4* Dr = (f32x4*)(lds + ((jq - 2) * 2 + qs) * 32768);
        #pragma unroll
        for (int g = 0; g < 8; ++g)
            #pragma unroll
            for (int r4 = 0; r4 < 4; ++r4) {
                f32x4 tv;
                #pragma unroll
                for (int e = 0; e < 4; ++e) tv[e] = acc[g][4 * r4 + e];
                Dr[(g * 4 + r4) * 64 + lane] = tv;
            }
    }
    __syncthreads();
    if (jq < 2) {
        const f32x4* Dr = (const f32x4*)(lds + (jq * 2 + qs) * 32768);
        #pragma unroll
        for (int g = 0; g < 8; ++g)
            #pragma unroll
            for (int r4 = 0; r4 < 4; ++r4) {
                f32x4 tv = Dr[(g * 4 + r4) * 64 + lane];
                #pragma unroll
                for (int e = 0; e < 4; ++e) acc[g][4 * r4 + e] += tv[e];
            }
    }
    __syncthreads();
    // phase B: jq1 dump -> D[2+qs]; jq0 add; jq0 dump final -> D[qs]
    if (jq == 1) {
        f32x4* Dr = (f32x4*)(lds + (2 + qs) * 32768);
        #pragma unroll
        for (int g = 0; g < 8; ++g)
            #pragma unroll
            for (int r4 = 0; r4 < 4; ++r4) {
                f32x4 tv;
                #pragma unroll
                for (int e = 0; e < 4; ++e) tv[e] = acc[g][4 * r4 + e];
                Dr[(g * 4 + r4) * 64 + lane] = tv;
            }
    }
    __syncthreads();
    if (jq == 0) {
        const f32x4* Dr = (const f32x4*)(lds + (2 + qs) * 32768);
        f32x4* Dw = (f32x4*)(lds + qs * 32768);
        #pragma unroll
        for (int g = 0; g < 8; ++g)
            #pragma unroll
            for (int r4 = 0; r4 < 4; ++r4) {
                f32x4 tv = Dr[(g * 4 + r4) * 64 + lane];
                #pragma unroll
                for (int e = 0; e < 4; ++e) tv[e] += acc[g][4 * r4 + e];
                Dw[(g * 4 + r4) * 64 + lane] = tv;
            }
    }
    __syncthreads();

    // ---- store: wave w -> q-subwave (w&1)==qs, g-pair (w>>1)==jq ----
    const float gma  = gamma[0];
    const float invL = 1.f / L;
    const f32x4* Ds = (const f32x4*)(lds + qs * 32768);
    const int i = iq + l31;
    #pragma unroll
    for (int gi = 0; gi < 2; ++gi) {
        const int g = jq * 2 + gi;
        #pragma unroll
        for (int r4 = 0; r4 < 4; ++r4) {
            f32x4 v = Ds[(g * 4 + r4) * 64 + lane];
            #pragma unroll
            for (int e = 0; e < 4; ++e) {
                const int c = 32 * g + e + 8 * r4 + 4 * h2;
                const size_t off = ((size_t)b * C_ + c) * N_ + i;
                out[off] = gma * v[e] * invL + x[off];
            }
        }
    }
}

extern "C" void kernel_launch(void* const* d_in, const int* in_sizes, int n_in,
                              void* d_out, int out_size, void* d_ws, size_t ws_size,
                              hipStream_t stream) {
    const float* x     = (const float*)d_in[0];
    const float* Wq    = (const float*)d_in[1];
    const float* bq    = (const float*)d_in[2];
    const float* Wk    = (const float*)d_in[3];
    const float* bk    = (const float*)d_in[4];
    const float* Wv    = (const float*)d_in[5];
    const float* bv    = (const float*)d_in[6];
    const float* gamma = (const float*)d_in[7];
    float* out = (float*)d_out;

    unsigned short* ws = (unsigned short*)d_ws;
    unsigned short* qb    = ws;                                 // B*N*32 bf16
    unsigned short* kfrag = qb + (size_t)B_ * N_ * INTER_;      // B*128*1024 bf16
    unsigned short* vfrag = kfrag + (size_t)B_ * 128 * 1024;    // B*128*8192 bf16
    unsigned short* wb    = vfrag + (size_t)B_ * 128 * 8192;    // 320*256 bf16

    prep_kernel<<<dim3(320), 256, 0, stream>>>(Wq, Wk, Wv, wb);
    qkv_kernel<<<dim3(B_ * (N_ / 64)), 256, 0, stream>>>(
        x, wb, bq, bk, bv, qb, kfrag, vfrag);
    attn_kernel<<<dim3(N_ / 64, B_), 512, 0, stream>>>(
        qb, kfrag, vfrag, x, gamma, out);
}